// Round 5
// baseline (164.779 us; speedup 1.0000x reference)
//
#include <hip/hip_runtime.h>

#define N_B 2
#define L_L 2048
#define E_E 1024
#define H_H 16
#define D_H 64
#define LDSP 72  // padded LDS row stride (ushorts) for qkv/out kernels

typedef __bf16 bf16x8 __attribute__((ext_vector_type(8)));
typedef float f32x4 __attribute__((ext_vector_type(4)));
typedef short s16x8 __attribute__((ext_vector_type(8)));
typedef unsigned short u16x4 __attribute__((ext_vector_type(4)));

__device__ __forceinline__ f32x4 mfma16(bf16x8 a, bf16x8 b, f32x4 c) {
  return __builtin_amdgcn_mfma_f32_16x16x32_bf16(a, b, c, 0, 0, 0);
}

__device__ __forceinline__ unsigned short f2bf(float x) {
  unsigned int u = __float_as_uint(x);
  u = (u + 0x7fffu + ((u >> 16) & 1u)) >> 16;
  return (unsigned short)u;
}

__device__ __forceinline__ unsigned int cvtpk(float lo, float hi) {
  unsigned int r;
  asm("v_cvt_pk_bf16_f32 %0, %1, %2" : "=v"(r) : "v"(lo), "v"(hi));
  return r;
}

__device__ __forceinline__ void swap32(unsigned int& a, unsigned int& b) {
  asm("v_permlane32_swap_b32 %0, %1" : "+v"(a), "+v"(b));
}
__device__ __forceinline__ void swap16(unsigned int& a, unsigned int& b) {
  asm("v_permlane16_swap_b32 %0, %1" : "+v"(a), "+v"(b));
}

// Build PV A-fragment (16 q-rows x 32 keys) from swapped-QK^T C-layout values.
// Input: this lane's 8 P values for keys {16kb+4lg+r}, kb in {lo: 0,1 / hi: 2,3}.
// Output frag: lane needs keys {8*lg + j}, j=0..7, pairs packed per VGPR.
__device__ __forceinline__ bf16x8 pack_frag(float p0, float p1, float p2, float p3,
                                            float p4, float p5, float p6, float p7) {
  unsigned int x0 = cvtpk(p0, p1), x1 = cvtpk(p2, p3);
  unsigned int x2 = cvtpk(p4, p5), x3 = cvtpk(p6, p7);
  swap32(x0, x2); swap16(x0, x2);   // -> t0, t2
  swap32(x1, x3); swap16(x1, x3);   // -> t1, t3
  union { unsigned int u[4]; bf16x8 v; } f;
  f.u[0] = x0; f.u[1] = x1; f.u[2] = x2; f.u[3] = x3;
  return f.v;
}

// K0: convert Wo (1M elems) and Wq/Wk/Wv (4096 each) to bf16.
__global__ __launch_bounds__(256) void cvt_weights_kernel(
    const float* __restrict__ Wo, const float* __restrict__ Wq,
    const float* __restrict__ Wk, const float* __restrict__ Wv,
    unsigned short* __restrict__ Wob, unsigned short* __restrict__ Wqb,
    unsigned short* __restrict__ Wkb, unsigned short* __restrict__ Wvb) {
  const int b = blockIdx.x;
  if (b < 1024) {
    const int i = b * 256 + threadIdx.x;
    const float4 f = ((const float4*)Wo)[i];
    u16x4 v = { f2bf(f.x), f2bf(f.y), f2bf(f.z), f2bf(f.w) };
    *(u16x4*)&Wob[(size_t)i * 4] = v;
  } else {
    const float* src = (b == 1024) ? Wq : (b == 1025) ? Wk : Wv;
    unsigned short* dst = (b == 1024) ? Wqb : (b == 1025) ? Wkb : Wvb;
    #pragma unroll
    for (int it = 0; it < 4; ++it) {
      const int i = it * 256 + threadIdx.x;
      const float4 f = ((const float4*)src)[i];
      u16x4 v = { f2bf(f.x), f2bf(f.y), f2bf(f.z), f2bf(f.w) };
      *(u16x4*)&dst[(size_t)i * 4] = v;
    }
  }
}

// K1: QKV projection as MFMA GEMM. Q is pre-scaled by (1/sqrt(E))*log2(e) so
// attention's QK^T lands directly in exp2 domain.
__global__ __launch_bounds__(256) void qkv_gemm_kernel(
    const float* __restrict__ EPq, const float* __restrict__ EPk, const float* __restrict__ EPv,
    const unsigned short* __restrict__ Wqb, const unsigned short* __restrict__ Wkb,
    const unsigned short* __restrict__ Wvb,
    const float* __restrict__ bq, const float* __restrict__ bk, const float* __restrict__ bv,
    unsigned short* __restrict__ Qb, unsigned short* __restrict__ Kb,
    unsigned short* __restrict__ Vtb) {
  __shared__ __attribute__((aligned(16))) unsigned short Xs[64][LDSP];
  __shared__ __attribute__((aligned(16))) unsigned short Ws[64][LDSP];
  const int tid = threadIdx.x;
  const int wid = tid >> 6;
  const int lane = tid & 63;
  const int lr = lane & 15;
  const int lg = lane >> 4;
  const int nh = blockIdx.x >> 5;
  const int l0 = (blockIdx.x & 31) * 64;
  const int n = nh >> 4;
  const int h = nh & 15;
  const float SCQ = 0.03125f * 1.44269504089f;

  #pragma unroll
  for (int mat = 0; mat < 3; ++mat) {
    const float* X = (mat == 0) ? EPq : (mat == 1) ? EPk : EPv;
    const unsigned short* W = (mat == 0) ? Wqb : (mat == 1) ? Wkb : Wvb;
    const float* bias = (mat == 0) ? bq : (mat == 1) ? bk : bv;
    const float osc = (mat == 0) ? SCQ : 1.0f;

    const float* xb = X + ((size_t)(n * L_L + l0)) * E_E + h * D_H;
    #pragma unroll
    for (int it = 0; it < 4; ++it) {
      const int idx = it * 256 + tid;
      const int row = idx >> 4, c = idx & 15;
      const float4 f = *(const float4*)(xb + (size_t)row * E_E + c * 4);
      u16x4 v = { f2bf(f.x), f2bf(f.y), f2bf(f.z), f2bf(f.w) };
      *(u16x4*)&Xs[row][c * 4] = v;
    }
    #pragma unroll
    for (int it = 0; it < 2; ++it) {
      const int idx = it * 256 + tid;
      *(s16x8*)&Ws[idx >> 3][(idx & 7) * 8] =
          *(const s16x8*)(W + (size_t)(idx >> 3) * 64 + (idx & 7) * 8);
    }
    __syncthreads();

    const bf16x8 a0 = *(const bf16x8*)&Xs[wid * 16 + lr][lg * 8];
    const bf16x8 a1 = *(const bf16x8*)&Xs[wid * 16 + lr][32 + lg * 8];
    f32x4 acc[4];
    #pragma unroll
    for (int t = 0; t < 4; ++t) {
      const float bb = bias[t * 16 + lr];
      acc[t] = f32x4{bb, bb, bb, bb};
      const bf16x8 b0 = *(const bf16x8*)&Ws[t * 16 + lr][lg * 8];
      const bf16x8 b1 = *(const bf16x8*)&Ws[t * 16 + lr][32 + lg * 8];
      acc[t] = mfma16(a0, b0, acc[t]);
      acc[t] = mfma16(a1, b1, acc[t]);
    }
    __syncthreads();

    #pragma unroll
    for (int t = 0; t < 4; ++t)
      #pragma unroll
      for (int r = 0; r < 4; ++r)
        Xs[wid * 16 + lg * 4 + r][t * 16 + lr] = f2bf(acc[t][r] * osc);
    __syncthreads();

    if (mat < 2) {
      unsigned short* dst = ((mat == 0) ? Qb : Kb) + ((size_t)nh * L_L + l0) * D_H;
      #pragma unroll
      for (int it = 0; it < 2; ++it) {
        const int idx = it * 256 + tid;
        const int row = idx >> 3, c = idx & 7;
        *(s16x8*)(dst + (size_t)row * D_H + c * 8) = *(s16x8*)&Xs[row][c * 8];
      }
    } else {
      #pragma unroll
      for (int it = 0; it < 2; ++it) {
        const int idx = it * 256 + tid;
        const int d = idx & 63, c = idx >> 6;
        s16x8 v;
        #pragma unroll
        for (int j = 0; j < 8; ++j) v[j] = (short)Xs[c * 8 + j][d];
        *(s16x8*)(Vtb + ((size_t)nh * D_H + d) * L_L + l0 + c * 8) = v;
      }
    }
    __syncthreads();
  }
}

// K2: flash attention. Zero LDS, zero barriers: K/V fragments straight from
// global (L2-resident per XCD), P kept in registers via cvt_pk + permlane swaps.
// grid = 512 blocks (XCD-swizzled), 256 threads = 4 waves x 32 q-rows.
__global__ __launch_bounds__(256, 2) void attn_mfma_kernel(
    const unsigned short* __restrict__ Qb, const unsigned short* __restrict__ Kb,
    const unsigned short* __restrict__ Vtb, unsigned short* __restrict__ Ab) {
  const int tid = threadIdx.x;
  const int wid = tid >> 6;
  const int lane = tid & 63;
  const int lr = lane & 15;
  const int lg = lane >> 4;

  // XCD-bijective swizzle: 512 blocks, 8 XCDs -> 64 contiguous per XCD (4 heads)
  const int bid = ((blockIdx.x & 7) << 6) + (blockIdx.x >> 3);
  const int nh = bid >> 4;
  const int q0w = ((bid & 15) << 7) + wid * 32;

  const unsigned short* gQ = Qb + ((size_t)nh * L_L + q0w) * D_H;
  const unsigned short* gK0 = Kb + (size_t)nh * L_L * D_H;
  const unsigned short* gV0 = Vtb + (size_t)nh * D_H * L_L;

  // Q B-fragments (q = qb*16+lr, d = c2*32+lg*8..)
  bf16x8 bQ[2][2];
  #pragma unroll
  for (int qb = 0; qb < 2; ++qb)
    #pragma unroll
    for (int c2 = 0; c2 < 2; ++c2)
      bQ[qb][c2] = *(const bf16x8*)(gQ + (qb * 16 + lr) * D_H + c2 * 32 + lg * 8);

  const s16x8 ones16 = {0x3F80,0x3F80,0x3F80,0x3F80,0x3F80,0x3F80,0x3F80,0x3F80};
  const bf16x8 ones = *(const bf16x8*)&ones16;

  // K A-frags (row = kb*16+lr, d-chunk c2) and V B-frags (d = t*16+lr, key-chunk c2)
  bf16x8 kfr[4][2], vfr[4][2];
  #pragma unroll
  for (int kb = 0; kb < 4; ++kb)
    #pragma unroll
    for (int c2 = 0; c2 < 2; ++c2) {
      kfr[kb][c2] = *(const bf16x8*)(gK0 + (size_t)(kb * 16 + lr) * D_H + c2 * 32 + lg * 8);
      vfr[kb][c2] = *(const bf16x8*)(gV0 + (size_t)(kb * 16 + lr) * L_L + c2 * 32 + lg * 8);
    }

  f32x4 acc0[4] = {f32x4{0,0,0,0},f32x4{0,0,0,0},f32x4{0,0,0,0},f32x4{0,0,0,0}};
  f32x4 acc1[4] = {f32x4{0,0,0,0},f32x4{0,0,0,0},f32x4{0,0,0,0},f32x4{0,0,0,0}};
  f32x4 lacc0 = {0,0,0,0}, lacc1 = {0,0,0,0};
  float m0 = -1e30f, m1 = -1e30f;

  for (int kt = 0; kt < L_L / 64; ++kt) {
    const int nxt = (kt + 1) & 31;

    // QK^T (scores already in exp2 domain: Q pre-scaled)
    float sv0[16], sv1[16];
    __builtin_amdgcn_s_setprio(1);
    #pragma unroll
    for (int kb = 0; kb < 4; ++kb) {
      f32x4 c0 = {0,0,0,0}, c1 = {0,0,0,0};
      c0 = mfma16(kfr[kb][0], bQ[0][0], c0); c0 = mfma16(kfr[kb][1], bQ[0][1], c0);
      c1 = mfma16(kfr[kb][0], bQ[1][0], c1); c1 = mfma16(kfr[kb][1], bQ[1][1], c1);
      #pragma unroll
      for (int r = 0; r < 4; ++r) { sv0[kb*4+r] = c0[r]; sv1[kb*4+r] = c1[r]; }
    }
    __builtin_amdgcn_s_setprio(0);

    // issue next-tile K loads (regs dead after QK^T issue)
    #pragma unroll
    for (int kb = 0; kb < 4; ++kb)
      #pragma unroll
      for (int c2 = 0; c2 < 2; ++c2)
        kfr[kb][c2] = *(const bf16x8*)(gK0 + (size_t)(nxt * 64 + kb * 16 + lr) * D_H +
                                       c2 * 32 + lg * 8);

    // in-lane max (16 keys per q)
    float mt0 = fmaxf(fmaxf(sv0[0], sv0[1]), fmaxf(sv0[2], sv0[3]));
    float mt1 = fmaxf(fmaxf(sv1[0], sv1[1]), fmaxf(sv1[2], sv1[3]));
    #pragma unroll
    for (int j = 4; j < 16; j += 4) {
      mt0 = fmaxf(mt0, fmaxf(fmaxf(sv0[j], sv0[j+1]), fmaxf(sv0[j+2], sv0[j+3])));
      mt1 = fmaxf(mt1, fmaxf(fmaxf(sv1[j], sv1[j+1]), fmaxf(sv1[j+2], sv1[j+3])));
    }

    // defer-max (T13, exp2 domain, THR=8)
    const bool defer = (mt0 - m0 <= 8.0f) && (mt1 - m1 <= 8.0f);
    if (!__all(defer)) {
      float v0 = fmaxf(mt0, __shfl_xor(mt0, 16)); v0 = fmaxf(v0, __shfl_xor(v0, 32));
      float v1 = fmaxf(mt1, __shfl_xor(mt1, 16)); v1 = fmaxf(v1, __shfl_xor(v1, 32));
      const float mn0 = fmaxf(m0, v0), mn1 = fmaxf(m1, v1);
      const float sc0f = exp2f(m0 - mn0), sc1f = exp2f(m1 - mn1);
      m0 = mn0; m1 = mn1;
      #pragma unroll
      for (int r = 0; r < 4; ++r) {
        const float sa0 = __shfl(sc0f, 4 * lg + r);
        const float sa1 = __shfl(sc1f, 4 * lg + r);
        #pragma unroll
        for (int t = 0; t < 4; ++t) { acc0[t][r] *= sa0; acc1[t][r] *= sa1; }
        lacc0[r] *= sa0; lacc1[r] *= sa1;
      }
    }

    #pragma unroll
    for (int j = 0; j < 16; ++j) { sv0[j] = exp2f(sv0[j] - m0); sv1[j] = exp2f(sv1[j] - m1); }

    // P -> A-fragments fully in-register (T12)
    bf16x8 aP0[2], aP1[2];
    aP0[0] = pack_frag(sv0[0], sv0[1], sv0[2], sv0[3], sv0[4], sv0[5], sv0[6], sv0[7]);
    aP0[1] = pack_frag(sv0[8], sv0[9], sv0[10], sv0[11], sv0[12], sv0[13], sv0[14], sv0[15]);
    aP1[0] = pack_frag(sv1[0], sv1[1], sv1[2], sv1[3], sv1[4], sv1[5], sv1[6], sv1[7]);
    aP1[1] = pack_frag(sv1[8], sv1[9], sv1[10], sv1[11], sv1[12], sv1[13], sv1[14], sv1[15]);

    // row-sum via ones-MFMA + PV
    __builtin_amdgcn_s_setprio(1);
    lacc0 = mfma16(aP0[0], ones, lacc0); lacc0 = mfma16(aP0[1], ones, lacc0);
    lacc1 = mfma16(aP1[0], ones, lacc1); lacc1 = mfma16(aP1[1], ones, lacc1);
    #pragma unroll
    for (int t = 0; t < 4; ++t) {
      acc0[t] = mfma16(aP0[0], vfr[t][0], acc0[t]); acc0[t] = mfma16(aP0[1], vfr[t][1], acc0[t]);
      acc1[t] = mfma16(aP1[0], vfr[t][0], acc1[t]); acc1[t] = mfma16(aP1[1], vfr[t][1], acc1[t]);
    }
    __builtin_amdgcn_s_setprio(0);

    // issue next-tile V loads
    #pragma unroll
    for (int t = 0; t < 4; ++t)
      #pragma unroll
      for (int c2 = 0; c2 < 2; ++c2)
        vfr[t][c2] = *(const bf16x8*)(gV0 + (size_t)(t * 16 + lr) * L_L + nxt * 64 +
                                      c2 * 32 + lg * 8);
  }

  // epilogue: normalize, write A bf16 token-major [n][l][E]
  const int n = nh >> 4, h = nh & 15;
  #pragma unroll
  for (int qb = 0; qb < 2; ++qb) {
    const f32x4& la = qb ? lacc1 : lacc0;
    f32x4* ac = qb ? acc1 : acc0;
    f32x4 inv;
    #pragma unroll
    for (int r = 0; r < 4; ++r) inv[r] = 1.0f / la[r];
    const int qbase = q0w + qb * 16 + 4 * lg;
    #pragma unroll
    for (int t = 0; t < 4; ++t)
      #pragma unroll
      for (int r = 0; r < 4; ++r)
        Ab[((size_t)(n * L_L + qbase + r)) * E_E + h * D_H + t * 16 + lr] =
            f2bf(ac[t][r] * inv[r]);
  }
}

// K3: out = A(bf16) @ Wo^T(bf16) + bo, fp32 out. 64x64 tile, 4 waves (2x2).
__global__ __launch_bounds__(256, 4) void out_gemm_kernel(
    const unsigned short* __restrict__ Ab, const unsigned short* __restrict__ Wob,
    const float* __restrict__ bo, float* __restrict__ out) {
  __shared__ __attribute__((aligned(16))) unsigned short As[64][LDSP];
  __shared__ __attribute__((aligned(16))) unsigned short Bs[64][LDSP];
  const int tid = threadIdx.x;
  const int wid = tid >> 6;
  const int lane = tid & 63;
  const int lr = lane & 15;
  const int lg = lane >> 4;
  const int m0 = (blockIdx.x >> 4) * 64;
  const int n0 = (blockIdx.x & 15) * 64;
  const int wr = wid >> 1, wc = wid & 1;

  f32x4 acc[2][2] = {{f32x4{0,0,0,0}, f32x4{0,0,0,0}}, {f32x4{0,0,0,0}, f32x4{0,0,0,0}}};

  for (int kt = 0; kt < 16; ++kt) {
    __syncthreads();
    for (int i = tid; i < 512; i += 256) {
      const int row = i >> 3, c = i & 7;
      *(s16x8*)&As[row][c * 8] =
          *(const s16x8*)(Ab + (size_t)(m0 + row) * E_E + kt * 64 + c * 8);
      *(s16x8*)&Bs[row][c * 8] =
          *(const s16x8*)(Wob + (size_t)(n0 + row) * E_E + kt * 64 + c * 8);
    }
    __syncthreads();
    #pragma unroll
    for (int kb = 0; kb < 2; ++kb) {
      const bf16x8 a0 = *(const bf16x8*)&As[wr * 32 + lr][kb * 32 + lg * 8];
      const bf16x8 a1 = *(const bf16x8*)&As[wr * 32 + 16 + lr][kb * 32 + lg * 8];
      const bf16x8 b0 = *(const bf16x8*)&Bs[wc * 32 + lr][kb * 32 + lg * 8];
      const bf16x8 b1 = *(const bf16x8*)&Bs[wc * 32 + 16 + lr][kb * 32 + lg * 8];
      acc[0][0] = mfma16(a0, b0, acc[0][0]);
      acc[0][1] = mfma16(a0, b1, acc[0][1]);
      acc[1][0] = mfma16(a1, b0, acc[1][0]);
      acc[1][1] = mfma16(a1, b1, acc[1][1]);
    }
  }
  #pragma unroll
  for (int mi = 0; mi < 2; ++mi)
    #pragma unroll
    for (int ni = 0; ni < 2; ++ni) {
      const int nn = n0 + wc * 32 + ni * 16 + lr;
      const float bb = bo[nn];
      #pragma unroll
      for (int r = 0; r < 4; ++r) {
        const int mm = m0 + wr * 32 + mi * 16 + lg * 4 + r;
        out[(size_t)mm * E_E + nn] = acc[mi][ni][r] + bb;
      }
    }
}

extern "C" void kernel_launch(void* const* d_in, const int* in_sizes, int n_in,
                              void* d_out, int out_size, void* d_ws, size_t ws_size,
                              hipStream_t stream) {
  const float* EPq = (const float*)d_in[0];
  const float* EPk = (const float*)d_in[1];
  const float* EPv = (const float*)d_in[2];
  const float* Wq  = (const float*)d_in[3];
  const float* bq  = (const float*)d_in[4];
  const float* Wk  = (const float*)d_in[5];
  const float* bk  = (const float*)d_in[6];
  const float* Wv  = (const float*)d_in[7];
  const float* bv  = (const float*)d_in[8];
  const float* Wo  = (const float*)d_in[9];
  const float* bo  = (const float*)d_in[10];
  float* out = (float*)d_out;

  unsigned short* ws = (unsigned short*)d_ws;
  const size_t SZ = (size_t)N_B * H_H * L_L * D_H;  // 4,194,304
  unsigned short* Qb  = ws;
  unsigned short* Kb  = Qb + SZ;
  unsigned short* Vtb = Kb + SZ;
  unsigned short* Ab  = Vtb + SZ;
  unsigned short* Wob = Ab + SZ;
  unsigned short* Wqb = Wob + (size_t)E_E * E_E;
  unsigned short* Wkb = Wqb + D_H * D_H;
  unsigned short* Wvb = Wkb + D_H * D_H;

  cvt_weights_kernel<<<1027, 256, 0, stream>>>(Wo, Wq, Wk, Wv, Wob, Wqb, Wkb, Wvb);
  qkv_gemm_kernel<<<1024, 256, 0, stream>>>(
      EPq, EPk, EPv, Wqb, Wkb, Wvb, bq, bk, bv, Qb, Kb, Vtb);
  attn_mfma_kernel<<<512, 256, 0, stream>>>(Qb, Kb, Vtb, Ab);
  out_gemm_kernel<<<1024, 256, 0, stream>>>(Ab, Wob, bo, out);
}

// Round 6
// 113.799 us; speedup vs baseline: 1.4480x; 1.4480x over previous
//
#include <hip/hip_runtime.h>

#define N_B 2
#define L_L 2048
#define E_E 1024
#define H_H 16
#define D_H 64
#define LDSP 72  // padded LDS row stride (ushorts) for qkv/out kernels

typedef __bf16 bf16x8 __attribute__((ext_vector_type(8)));
typedef float f32x4 __attribute__((ext_vector_type(4)));
typedef short s16x8 __attribute__((ext_vector_type(8)));
typedef unsigned short u16x4 __attribute__((ext_vector_type(4)));

__device__ __forceinline__ f32x4 mfma16(bf16x8 a, bf16x8 b, f32x4 c) {
  return __builtin_amdgcn_mfma_f32_16x16x32_bf16(a, b, c, 0, 0, 0);
}

__device__ __forceinline__ unsigned short f2bf(float x) {
  unsigned int u = __float_as_uint(x);
  u = (u + 0x7fffu + ((u >> 16) & 1u)) >> 16;
  return (unsigned short)u;
}

__device__ __forceinline__ unsigned int cvtpk(float lo, float hi) {
  unsigned int r;
  asm("v_cvt_pk_bf16_f32 %0, %1, %2" : "=v"(r) : "v"(lo), "v"(hi));
  return r;
}

__device__ __forceinline__ void swap32(unsigned int& a, unsigned int& b) {
  asm("v_permlane32_swap_b32 %0, %1" : "+v"(a), "+v"(b));
}
__device__ __forceinline__ void swap16(unsigned int& a, unsigned int& b) {
  asm("v_permlane16_swap_b32 %0, %1" : "+v"(a), "+v"(b));
}

// async global->LDS 16B DMA (width-16 variant; dest must be linear per wave)
__device__ __forceinline__ void gload16(const void* g, void* l) {
  __builtin_amdgcn_global_load_lds(
      (__attribute__((address_space(1))) void*)g,
      (__attribute__((address_space(3))) void*)l, 16, 0, 0);
}

// Build PV A-fragment (16 q-rows x 32 keys) from swapped-QK^T C-layout values.
__device__ __forceinline__ bf16x8 pack_frag(float p0, float p1, float p2, float p3,
                                            float p4, float p5, float p6, float p7) {
  unsigned int x0 = cvtpk(p0, p1), x1 = cvtpk(p2, p3);
  unsigned int x2 = cvtpk(p4, p5), x3 = cvtpk(p6, p7);
  swap32(x0, x2); swap16(x0, x2);
  swap32(x1, x3); swap16(x1, x3);
  union { unsigned int u[4]; bf16x8 v; } f;
  f.u[0] = x0; f.u[1] = x1; f.u[2] = x2; f.u[3] = x3;
  return f.v;
}

// K0: convert Wo (1M elems) and Wq/Wk/Wv (4096 each) to bf16.
__global__ __launch_bounds__(256) void cvt_weights_kernel(
    const float* __restrict__ Wo, const float* __restrict__ Wq,
    const float* __restrict__ Wk, const float* __restrict__ Wv,
    unsigned short* __restrict__ Wob, unsigned short* __restrict__ Wqb,
    unsigned short* __restrict__ Wkb, unsigned short* __restrict__ Wvb) {
  const int b = blockIdx.x;
  if (b < 1024) {
    const int i = b * 256 + threadIdx.x;
    const float4 f = ((const float4*)Wo)[i];
    u16x4 v = { f2bf(f.x), f2bf(f.y), f2bf(f.z), f2bf(f.w) };
    *(u16x4*)&Wob[(size_t)i * 4] = v;
  } else {
    const float* src = (b == 1024) ? Wq : (b == 1025) ? Wk : Wv;
    unsigned short* dst = (b == 1024) ? Wqb : (b == 1025) ? Wkb : Wvb;
    #pragma unroll
    for (int it = 0; it < 4; ++it) {
      const int i = it * 256 + threadIdx.x;
      const float4 f = ((const float4*)src)[i];
      u16x4 v = { f2bf(f.x), f2bf(f.y), f2bf(f.z), f2bf(f.w) };
      *(u16x4*)&dst[(size_t)i * 4] = v;
    }
  }
}

// K1: QKV projection as MFMA GEMM. Q pre-scaled by (1/sqrt(E))*log2(e).
__global__ __launch_bounds__(256) void qkv_gemm_kernel(
    const float* __restrict__ EPq, const float* __restrict__ EPk, const float* __restrict__ EPv,
    const unsigned short* __restrict__ Wqb, const unsigned short* __restrict__ Wkb,
    const unsigned short* __restrict__ Wvb,
    const float* __restrict__ bq, const float* __restrict__ bk, const float* __restrict__ bv,
    unsigned short* __restrict__ Qb, unsigned short* __restrict__ Kb,
    unsigned short* __restrict__ Vtb) {
  __shared__ __attribute__((aligned(16))) unsigned short Xs[64][LDSP];
  __shared__ __attribute__((aligned(16))) unsigned short Ws[64][LDSP];
  const int tid = threadIdx.x;
  const int wid = tid >> 6;
  const int lane = tid & 63;
  const int lr = lane & 15;
  const int lg = lane >> 4;
  const int nh = blockIdx.x >> 5;
  const int l0 = (blockIdx.x & 31) * 64;
  const int n = nh >> 4;
  const int h = nh & 15;
  const float SCQ = 0.03125f * 1.44269504089f;

  #pragma unroll
  for (int mat = 0; mat < 3; ++mat) {
    const float* X = (mat == 0) ? EPq : (mat == 1) ? EPk : EPv;
    const unsigned short* W = (mat == 0) ? Wqb : (mat == 1) ? Wkb : Wvb;
    const float* bias = (mat == 0) ? bq : (mat == 1) ? bk : bv;
    const float osc = (mat == 0) ? SCQ : 1.0f;

    const float* xb = X + ((size_t)(n * L_L + l0)) * E_E + h * D_H;
    #pragma unroll
    for (int it = 0; it < 4; ++it) {
      const int idx = it * 256 + tid;
      const int row = idx >> 4, c = idx & 15;
      const float4 f = *(const float4*)(xb + (size_t)row * E_E + c * 4);
      u16x4 v = { f2bf(f.x), f2bf(f.y), f2bf(f.z), f2bf(f.w) };
      *(u16x4*)&Xs[row][c * 4] = v;
    }
    #pragma unroll
    for (int it = 0; it < 2; ++it) {
      const int idx = it * 256 + tid;
      *(s16x8*)&Ws[idx >> 3][(idx & 7) * 8] =
          *(const s16x8*)(W + (size_t)(idx >> 3) * 64 + (idx & 7) * 8);
    }
    __syncthreads();

    const bf16x8 a0 = *(const bf16x8*)&Xs[wid * 16 + lr][lg * 8];
    const bf16x8 a1 = *(const bf16x8*)&Xs[wid * 16 + lr][32 + lg * 8];
    f32x4 acc[4];
    #pragma unroll
    for (int t = 0; t < 4; ++t) {
      const float bb = bias[t * 16 + lr];
      acc[t] = f32x4{bb, bb, bb, bb};
      const bf16x8 b0 = *(const bf16x8*)&Ws[t * 16 + lr][lg * 8];
      const bf16x8 b1 = *(const bf16x8*)&Ws[t * 16 + lr][32 + lg * 8];
      acc[t] = mfma16(a0, b0, acc[t]);
      acc[t] = mfma16(a1, b1, acc[t]);
    }
    __syncthreads();

    #pragma unroll
    for (int t = 0; t < 4; ++t)
      #pragma unroll
      for (int r = 0; r < 4; ++r)
        Xs[wid * 16 + lg * 4 + r][t * 16 + lr] = f2bf(acc[t][r] * osc);
    __syncthreads();

    if (mat < 2) {
      unsigned short* dst = ((mat == 0) ? Qb : Kb) + ((size_t)nh * L_L + l0) * D_H;
      #pragma unroll
      for (int it = 0; it < 2; ++it) {
        const int idx = it * 256 + tid;
        const int row = idx >> 3, c = idx & 7;
        *(s16x8*)(dst + (size_t)row * D_H + c * 8) = *(s16x8*)&Xs[row][c * 8];
      }
    } else {
      #pragma unroll
      for (int it = 0; it < 2; ++it) {
        const int idx = it * 256 + tid;
        const int d = idx & 63, c = idx >> 6;
        s16x8 v;
        #pragma unroll
        for (int j = 0; j < 8; ++j) v[j] = (short)Xs[c * 8 + j][d];
        *(s16x8*)(Vtb + ((size_t)nh * D_H + d) * L_L + l0 + c * 8) = v;
      }
    }
    __syncthreads();
  }
}

// K2: flash attention. K/V staged in LDS via global_load_lds (swizzled source,
// linear dest), double-buffered, 1 barrier/iter; P fully in-register (T12).
// grid = 512 blocks (XCD-swizzled), 256 threads = 4 waves x 32 q-rows.
__global__ __launch_bounds__(256, 2) void attn_mfma_kernel(
    const unsigned short* __restrict__ Qb, const unsigned short* __restrict__ Kb,
    const unsigned short* __restrict__ Vtb, unsigned short* __restrict__ Ab) {
  __shared__ __attribute__((aligned(16))) unsigned short KS[2][64][64];
  __shared__ __attribute__((aligned(16))) unsigned short VS[2][64][64];

  const int tid = threadIdx.x;
  const int wid = tid >> 6;
  const int lane = tid & 63;
  const int lr = lane & 15;
  const int lg = lane >> 4;

  // XCD-bijective swizzle: 512 blocks, 8 XCDs -> 64 contiguous per XCD
  const int bid = ((blockIdx.x & 7) << 6) + (blockIdx.x >> 3);
  const int nh = bid >> 4;
  const int q0w = ((bid & 15) << 7) + wid * 32;

  const unsigned short* gQ = Qb + ((size_t)nh * L_L + q0w) * D_H;
  const unsigned short* gK0 = Kb + (size_t)nh * L_L * D_H;
  const unsigned short* gV0 = Vtb + (size_t)nh * D_H * L_L;

  // Q B-fragments (q = qb*16+lr, d = c2*32+lg*8..)
  bf16x8 bQ[2][2];
  #pragma unroll
  for (int qb = 0; qb < 2; ++qb)
    #pragma unroll
    for (int c2 = 0; c2 < 2; ++c2)
      bQ[qb][c2] = *(const bf16x8*)(gQ + (qb * 16 + lr) * D_H + c2 * 32 + lg * 8);

  const s16x8 ones16 = {0x3F80,0x3F80,0x3F80,0x3F80,0x3F80,0x3F80,0x3F80,0x3F80};
  const bf16x8 ones = *(const bf16x8*)&ones16;

  // staging indices: thread handles b128 chunks i and i+256 of the 64x64 tile
  const int srow0 = tid >> 3, sch0 = tid & 7;
  const int srow1 = srow0 + 32;
  // source chunk is XOR-permuted so linear LDS ends up swizzle-readable
  const int kc0 = (sch0 ^ (srow0 & 7)) * 8;
  const int kc1 = (sch0 ^ (srow1 & 7)) * 8;

  #define STAGE(buf, ktoff)                                                     \
    do {                                                                        \
      unsigned short* kd = &KS[buf][0][0];                                      \
      unsigned short* vd = &VS[buf][0][0];                                      \
      gload16(gK0 + (size_t)((ktoff) * 64 + srow0) * D_H + kc0,                 \
              kd + srow0 * 64 + sch0 * 8);                                      \
      gload16(gK0 + (size_t)((ktoff) * 64 + srow1) * D_H + kc1,                 \
              kd + srow1 * 64 + sch0 * 8);                                      \
      gload16(gV0 + (size_t)srow0 * L_L + (ktoff) * 64 + kc0,                   \
              vd + srow0 * 64 + sch0 * 8);                                      \
      gload16(gV0 + (size_t)srow1 * L_L + (ktoff) * 64 + kc1,                   \
              vd + srow1 * 64 + sch0 * 8);                                      \
    } while (0)

  STAGE(0, 0);
  __syncthreads();

  f32x4 acc0[4] = {f32x4{0,0,0,0},f32x4{0,0,0,0},f32x4{0,0,0,0},f32x4{0,0,0,0}};
  f32x4 acc1[4] = {f32x4{0,0,0,0},f32x4{0,0,0,0},f32x4{0,0,0,0},f32x4{0,0,0,0}};
  f32x4 lacc0 = {0,0,0,0}, lacc1 = {0,0,0,0};
  float m0 = -1e30f, m1 = -1e30f;
  int cur = 0;

  for (int kt = 0; kt < L_L / 64; ++kt) {
    // issue next tile's DMA into the other buffer (completes before barrier)
    STAGE(cur ^ 1, ((kt + 1) & 31));

    const char* Kcur = (const char*)&KS[cur][0][0];
    const char* Vcur = (const char*)&VS[cur][0][0];

    // QK^T swapped (A=K, B=Q): lane holds keys {16kb+4lg+r} for q = lr / 16+lr
    float sv0[16], sv1[16];
    __builtin_amdgcn_s_setprio(1);
    #pragma unroll
    for (int kb = 0; kb < 4; ++kb) {
      const int row = kb * 16 + lr;
      const bf16x8 a0 = *(const bf16x8*)(Kcur + row * 128 + ((lg ^ (row & 7)) << 4));
      const bf16x8 a1 = *(const bf16x8*)(Kcur + row * 128 + (((4 + lg) ^ (row & 7)) << 4));
      f32x4 c0 = {0,0,0,0}, c1 = {0,0,0,0};
      c0 = mfma16(a0, bQ[0][0], c0); c0 = mfma16(a1, bQ[0][1], c0);
      c1 = mfma16(a0, bQ[1][0], c1); c1 = mfma16(a1, bQ[1][1], c1);
      #pragma unroll
      for (int r = 0; r < 4; ++r) { sv0[kb*4+r] = c0[r]; sv1[kb*4+r] = c1[r]; }
    }
    __builtin_amdgcn_s_setprio(0);

    // in-lane max (16 keys per q)
    float mt0 = fmaxf(fmaxf(sv0[0], sv0[1]), fmaxf(sv0[2], sv0[3]));
    float mt1 = fmaxf(fmaxf(sv1[0], sv1[1]), fmaxf(sv1[2], sv1[3]));
    #pragma unroll
    for (int j = 4; j < 16; j += 4) {
      mt0 = fmaxf(mt0, fmaxf(fmaxf(sv0[j], sv0[j+1]), fmaxf(sv0[j+2], sv0[j+3])));
      mt1 = fmaxf(mt1, fmaxf(fmaxf(sv1[j], sv1[j+1]), fmaxf(sv1[j+2], sv1[j+3])));
    }

    // defer-max (T13, exp2 domain, THR=8)
    const bool defer = (mt0 - m0 <= 8.0f) && (mt1 - m1 <= 8.0f);
    if (!__all(defer)) {
      float v0 = fmaxf(mt0, __shfl_xor(mt0, 16)); v0 = fmaxf(v0, __shfl_xor(v0, 32));
      float v1 = fmaxf(mt1, __shfl_xor(mt1, 16)); v1 = fmaxf(v1, __shfl_xor(v1, 32));
      const float mn0 = fmaxf(m0, v0), mn1 = fmaxf(m1, v1);
      const float sc0f = exp2f(m0 - mn0), sc1f = exp2f(m1 - mn1);
      m0 = mn0; m1 = mn1;
      #pragma unroll
      for (int r = 0; r < 4; ++r) {
        const float sa0 = __shfl(sc0f, 4 * lg + r);
        const float sa1 = __shfl(sc1f, 4 * lg + r);
        #pragma unroll
        for (int t = 0; t < 4; ++t) { acc0[t][r] *= sa0; acc1[t][r] *= sa1; }
        lacc0[r] *= sa0; lacc1[r] *= sa1;
      }
    }

    #pragma unroll
    for (int j = 0; j < 16; ++j) { sv0[j] = exp2f(sv0[j] - m0); sv1[j] = exp2f(sv1[j] - m1); }

    // P -> A-fragments fully in-register (T12)
    bf16x8 aP0[2], aP1[2];
    aP0[0] = pack_frag(sv0[0], sv0[1], sv0[2], sv0[3], sv0[4], sv0[5], sv0[6], sv0[7]);
    aP0[1] = pack_frag(sv0[8], sv0[9], sv0[10], sv0[11], sv0[12], sv0[13], sv0[14], sv0[15]);
    aP1[0] = pack_frag(sv1[0], sv1[1], sv1[2], sv1[3], sv1[4], sv1[5], sv1[6], sv1[7]);
    aP1[1] = pack_frag(sv1[8], sv1[9], sv1[10], sv1[11], sv1[12], sv1[13], sv1[14], sv1[15]);

    // row-sum via ones-MFMA + PV (V B-frags from swizzled LDS)
    __builtin_amdgcn_s_setprio(1);
    lacc0 = mfma16(aP0[0], ones, lacc0); lacc0 = mfma16(aP0[1], ones, lacc0);
    lacc1 = mfma16(aP1[0], ones, lacc1); lacc1 = mfma16(aP1[1], ones, lacc1);
    #pragma unroll
    for (int t = 0; t < 4; ++t) {
      const int row = t * 16 + lr;
      const bf16x8 v0 = *(const bf16x8*)(Vcur + row * 128 + ((lg ^ (row & 7)) << 4));
      const bf16x8 v1 = *(const bf16x8*)(Vcur + row * 128 + (((4 + lg) ^ (row & 7)) << 4));
      acc0[t] = mfma16(aP0[0], v0, acc0[t]); acc0[t] = mfma16(aP0[1], v1, acc0[t]);
      acc1[t] = mfma16(aP1[0], v0, acc1[t]); acc1[t] = mfma16(aP1[1], v1, acc1[t]);
    }
    __builtin_amdgcn_s_setprio(0);

    // one barrier per iter: drains DMA (vmcnt) + LDS reads, flips buffers
    __syncthreads();
    cur ^= 1;
  }
  #undef STAGE

  // epilogue: normalize, write A bf16 token-major [n][l][E]
  const int n = nh >> 4, h = nh & 15;
  #pragma unroll
  for (int qb = 0; qb < 2; ++qb) {
    const f32x4& la = qb ? lacc1 : lacc0;
    f32x4* ac = qb ? acc1 : acc0;
    f32x4 inv;
    #pragma unroll
    for (int r = 0; r < 4; ++r) inv[r] = 1.0f / la[r];
    const int qbase = q0w + qb * 16 + 4 * lg;
    #pragma unroll
    for (int t = 0; t < 4; ++t)
      #pragma unroll
      for (int r = 0; r < 4; ++r)
        Ab[((size_t)(n * L_L + qbase + r)) * E_E + h * D_H + t * 16 + lr] =
            f2bf(ac[t][r] * inv[r]);
  }
}

// K3: out = A(bf16) @ Wo^T(bf16) + bo, fp32 out. 64x64 tile, 4 waves (2x2).
__global__ __launch_bounds__(256, 4) void out_gemm_kernel(
    const unsigned short* __restrict__ Ab, const unsigned short* __restrict__ Wob,
    const float* __restrict__ bo, float* __restrict__ out) {
  __shared__ __attribute__((aligned(16))) unsigned short As[64][LDSP];
  __shared__ __attribute__((aligned(16))) unsigned short Bs[64][LDSP];
  const int tid = threadIdx.x;
  const int wid = tid >> 6;
  const int lane = tid & 63;
  const int lr = lane & 15;
  const int lg = lane >> 4;
  const int m0 = (blockIdx.x >> 4) * 64;
  const int n0 = (blockIdx.x & 15) * 64;
  const int wr = wid >> 1, wc = wid & 1;

  f32x4 acc[2][2] = {{f32x4{0,0,0,0}, f32x4{0,0,0,0}}, {f32x4{0,0,0,0}, f32x4{0,0,0,0}}};

  for (int kt = 0; kt < 16; ++kt) {
    __syncthreads();
    for (int i = tid; i < 512; i += 256) {
      const int row = i >> 3, c = i & 7;
      *(s16x8*)&As[row][c * 8] =
          *(const s16x8*)(Ab + (size_t)(m0 + row) * E_E + kt * 64 + c * 8);
      *(s16x8*)&Bs[row][c * 8] =
          *(const s16x8*)(Wob + (size_t)(n0 + row) * E_E + kt * 64 + c * 8);
    }
    __syncthreads();
    #pragma unroll
    for (int kb = 0; kb < 2; ++kb) {
      const bf16x8 a0 = *(const bf16x8*)&As[wr * 32 + lr][kb * 32 + lg * 8];
      const bf16x8 a1 = *(const bf16x8*)&As[wr * 32 + 16 + lr][kb * 32 + lg * 8];
      const bf16x8 b0 = *(const bf16x8*)&Bs[wc * 32 + lr][kb * 32 + lg * 8];
      const bf16x8 b1 = *(const bf16x8*)&Bs[wc * 32 + 16 + lr][kb * 32 + lg * 8];
      acc[0][0] = mfma16(a0, b0, acc[0][0]);
      acc[0][1] = mfma16(a0, b1, acc[0][1]);
      acc[1][0] = mfma16(a1, b0, acc[1][0]);
      acc[1][1] = mfma16(a1, b1, acc[1][1]);
    }
  }
  #pragma unroll
  for (int mi = 0; mi < 2; ++mi)
    #pragma unroll
    for (int ni = 0; ni < 2; ++ni) {
      const int nn = n0 + wc * 32 + ni * 16 + lr;
      const float bb = bo[nn];
      #pragma unroll
      for (int r = 0; r < 4; ++r) {
        const int mm = m0 + wr * 32 + mi * 16 + lg * 4 + r;
        out[(size_t)mm * E_E + nn] = acc[mi][ni][r] + bb;
      }
    }
}

extern "C" void kernel_launch(void* const* d_in, const int* in_sizes, int n_in,
                              void* d_out, int out_size, void* d_ws, size_t ws_size,
                              hipStream_t stream) {
  const float* EPq = (const float*)d_in[0];
  const float* EPk = (const float*)d_in[1];
  const float* EPv = (const float*)d_in[2];
  const float* Wq  = (const float*)d_in[3];
  const float* bq  = (const float*)d_in[4];
  const float* Wk  = (const float*)d_in[5];
  const float* bk  = (const float*)d_in[6];
  const float* Wv  = (const float*)d_in[7];
  const float* bv  = (const float*)d_in[8];
  const float* Wo  = (const float*)d_in[9];
  const float* bo  = (const float*)d_in[10];
  float* out = (float*)d_out;

  unsigned short* ws = (unsigned short*)d_ws;
  const size_t SZ = (size_t)N_B * H_H * L_L * D_H;  // 4,194,304
  unsigned short* Qb  = ws;
  unsigned short* Kb  = Qb + SZ;
  unsigned short* Vtb = Kb + SZ;
  unsigned short* Ab  = Vtb + SZ;
  unsigned short* Wob = Ab + SZ;
  unsigned short* Wqb = Wob + (size_t)E_E * E_E;
  unsigned short* Wkb = Wqb + D_H * D_H;
  unsigned short* Wvb = Wkb + D_H * D_H;

  cvt_weights_kernel<<<1027, 256, 0, stream>>>(Wo, Wq, Wk, Wv, Wob, Wqb, Wkb, Wvb);
  qkv_gemm_kernel<<<1024, 256, 0, stream>>>(
      EPq, EPk, EPv, Wqb, Wkb, Wvb, bq, bk, bv, Qb, Kb, Vtb);
  attn_mfma_kernel<<<512, 256, 0, stream>>>(Qb, Kb, Vtb, Ab);
  out_gemm_kernel<<<1024, 256, 0, stream>>>(Ab, Wob, bo, out);
}

// Round 7
// 91.313 us; speedup vs baseline: 1.8046x; 1.2463x over previous
//
#include <hip/hip_runtime.h>

#define N_B 2
#define L_L 2048
#define E_E 1024
#define H_H 16
#define D_H 64
#define LDSP 72  // padded LDS row stride (ushorts) for qkv/out kernels

typedef __bf16 bf16x8 __attribute__((ext_vector_type(8)));
typedef float f32x4 __attribute__((ext_vector_type(4)));
typedef short s16x8 __attribute__((ext_vector_type(8)));
typedef unsigned short u16x4 __attribute__((ext_vector_type(4)));

__device__ __forceinline__ f32x4 mfma16(bf16x8 a, bf16x8 b, f32x4 c) {
  return __builtin_amdgcn_mfma_f32_16x16x32_bf16(a, b, c, 0, 0, 0);
}

__device__ __forceinline__ unsigned short f2bf(float x) {
  unsigned int u = __float_as_uint(x);
  u = (u + 0x7fffu + ((u >> 16) & 1u)) >> 16;
  return (unsigned short)u;
}

__device__ __forceinline__ unsigned int cvtpk(float lo, float hi) {
  unsigned int r;
  asm("v_cvt_pk_bf16_f32 %0, %1, %2" : "=v"(r) : "v"(lo), "v"(hi));
  return r;
}

__device__ __forceinline__ void swap32(unsigned int& a, unsigned int& b) {
  asm("v_permlane32_swap_b32 %0, %1" : "+v"(a), "+v"(b));
}
__device__ __forceinline__ void swap16(unsigned int& a, unsigned int& b) {
  asm("v_permlane16_swap_b32 %0, %1" : "+v"(a), "+v"(b));
}

__device__ __forceinline__ float max3f(float a, float b, float c) {
  float r;
  asm("v_max3_f32 %0, %1, %2, %3" : "=v"(r) : "v"(a), "v"(b), "v"(c));
  return r;
}

__device__ __forceinline__ float exp2a(float x) {  // 2^x, single v_exp_f32
  float r;
  asm("v_exp_f32 %0, %1" : "=v"(r) : "v"(x));
  return r;
}

// async global->LDS 16B DMA (dest linear per wave)
__device__ __forceinline__ void gload16(const void* g, void* l) {
  __builtin_amdgcn_global_load_lds(
      (__attribute__((address_space(1))) void*)g,
      (__attribute__((address_space(3))) void*)l, 16, 0, 0);
}

// Build PV A-fragment from swapped-QK^T C-layout values (in-register, T12).
__device__ __forceinline__ bf16x8 pack_frag(float p0, float p1, float p2, float p3,
                                            float p4, float p5, float p6, float p7) {
  unsigned int x0 = cvtpk(p0, p1), x1 = cvtpk(p2, p3);
  unsigned int x2 = cvtpk(p4, p5), x3 = cvtpk(p6, p7);
  swap32(x0, x2); swap16(x0, x2);
  swap32(x1, x3); swap16(x1, x3);
  union { unsigned int u[4]; bf16x8 v; } f;
  f.u[0] = x0; f.u[1] = x1; f.u[2] = x2; f.u[3] = x3;
  return f.v;
}

// K0: convert Wo (1M elems) and Wq/Wk/Wv (4096 each) to bf16.
__global__ __launch_bounds__(256) void cvt_weights_kernel(
    const float* __restrict__ Wo, const float* __restrict__ Wq,
    const float* __restrict__ Wk, const float* __restrict__ Wv,
    unsigned short* __restrict__ Wob, unsigned short* __restrict__ Wqb,
    unsigned short* __restrict__ Wkb, unsigned short* __restrict__ Wvb) {
  const int b = blockIdx.x;
  if (b < 1024) {
    const int i = b * 256 + threadIdx.x;
    const float4 f = ((const float4*)Wo)[i];
    u16x4 v = { f2bf(f.x), f2bf(f.y), f2bf(f.z), f2bf(f.w) };
    *(u16x4*)&Wob[(size_t)i * 4] = v;
  } else {
    const float* src = (b == 1024) ? Wq : (b == 1025) ? Wk : Wv;
    unsigned short* dst = (b == 1024) ? Wqb : (b == 1025) ? Wkb : Wvb;
    #pragma unroll
    for (int it = 0; it < 4; ++it) {
      const int i = it * 256 + threadIdx.x;
      const float4 f = ((const float4*)src)[i];
      u16x4 v = { f2bf(f.x), f2bf(f.y), f2bf(f.z), f2bf(f.w) };
      *(u16x4*)&dst[(size_t)i * 4] = v;
    }
  }
}

// K1: QKV projection as MFMA GEMM. Q pre-scaled by (1/sqrt(E))*log2(e).
__global__ __launch_bounds__(256) void qkv_gemm_kernel(
    const float* __restrict__ EPq, const float* __restrict__ EPk, const float* __restrict__ EPv,
    const unsigned short* __restrict__ Wqb, const unsigned short* __restrict__ Wkb,
    const unsigned short* __restrict__ Wvb,
    const float* __restrict__ bq, const float* __restrict__ bk, const float* __restrict__ bv,
    unsigned short* __restrict__ Qb, unsigned short* __restrict__ Kb,
    unsigned short* __restrict__ Vtb) {
  __shared__ __attribute__((aligned(16))) unsigned short Xs[64][LDSP];
  __shared__ __attribute__((aligned(16))) unsigned short Ws[64][LDSP];
  const int tid = threadIdx.x;
  const int wid = tid >> 6;
  const int lane = tid & 63;
  const int lr = lane & 15;
  const int lg = lane >> 4;
  const int nh = blockIdx.x >> 5;
  const int l0 = (blockIdx.x & 31) * 64;
  const int n = nh >> 4;
  const int h = nh & 15;
  const float SCQ = 0.03125f * 1.44269504089f;

  #pragma unroll
  for (int mat = 0; mat < 3; ++mat) {
    const float* X = (mat == 0) ? EPq : (mat == 1) ? EPk : EPv;
    const unsigned short* W = (mat == 0) ? Wqb : (mat == 1) ? Wkb : Wvb;
    const float* bias = (mat == 0) ? bq : (mat == 1) ? bk : bv;
    const float osc = (mat == 0) ? SCQ : 1.0f;

    const float* xb = X + ((size_t)(n * L_L + l0)) * E_E + h * D_H;
    #pragma unroll
    for (int it = 0; it < 4; ++it) {
      const int idx = it * 256 + tid;
      const int row = idx >> 4, c = idx & 15;
      const float4 f = *(const float4*)(xb + (size_t)row * E_E + c * 4);
      u16x4 v = { f2bf(f.x), f2bf(f.y), f2bf(f.z), f2bf(f.w) };
      *(u16x4*)&Xs[row][c * 4] = v;
    }
    #pragma unroll
    for (int it = 0; it < 2; ++it) {
      const int idx = it * 256 + tid;
      *(s16x8*)&Ws[idx >> 3][(idx & 7) * 8] =
          *(const s16x8*)(W + (size_t)(idx >> 3) * 64 + (idx & 7) * 8);
    }
    __syncthreads();

    const bf16x8 a0 = *(const bf16x8*)&Xs[wid * 16 + lr][lg * 8];
    const bf16x8 a1 = *(const bf16x8*)&Xs[wid * 16 + lr][32 + lg * 8];
    f32x4 acc[4];
    #pragma unroll
    for (int t = 0; t < 4; ++t) {
      const float bb = bias[t * 16 + lr];
      acc[t] = f32x4{bb, bb, bb, bb};
      const bf16x8 b0 = *(const bf16x8*)&Ws[t * 16 + lr][lg * 8];
      const bf16x8 b1 = *(const bf16x8*)&Ws[t * 16 + lr][32 + lg * 8];
      acc[t] = mfma16(a0, b0, acc[t]);
      acc[t] = mfma16(a1, b1, acc[t]);
    }
    __syncthreads();

    #pragma unroll
    for (int t = 0; t < 4; ++t)
      #pragma unroll
      for (int r = 0; r < 4; ++r)
        Xs[wid * 16 + lg * 4 + r][t * 16 + lr] = f2bf(acc[t][r] * osc);
    __syncthreads();

    if (mat < 2) {
      unsigned short* dst = ((mat == 0) ? Qb : Kb) + ((size_t)nh * L_L + l0) * D_H;
      #pragma unroll
      for (int it = 0; it < 2; ++it) {
        const int idx = it * 256 + tid;
        const int row = idx >> 3, c = idx & 7;
        *(s16x8*)(dst + (size_t)row * D_H + c * 8) = *(s16x8*)&Xs[row][c * 8];
      }
    } else {
      #pragma unroll
      for (int it = 0; it < 2; ++it) {
        const int idx = it * 256 + tid;
        const int d = idx & 63, c = idx >> 6;
        s16x8 v;
        #pragma unroll
        for (int j = 0; j < 8; ++j) v[j] = (short)Xs[c * 8 + j][d];
        *(s16x8*)(Vtb + ((size_t)nh * D_H + d) * L_L + l0 + c * 8) = v;
      }
    }
    __syncthreads();
  }
}

// K2: flash attention with in-block split-K.
// 512 blocks (32 nh x 16 q-tiles of 128) x 512 threads = 8 waves:
// waves 0-3 (kw=0) do keys [0,1024), waves 4-7 (kw=1) keys [1024,2048),
// same 128 q rows; partials merged in LDS at the end.
__global__ __launch_bounds__(512, 4) void attn_mfma_kernel(
    const unsigned short* __restrict__ Qb, const unsigned short* __restrict__ Kb,
    const unsigned short* __restrict__ Vtb, unsigned short* __restrict__ Ab) {
  __shared__ __attribute__((aligned(16))) unsigned short KS[2][2][64][64]; // [half][dbuf]
  __shared__ __attribute__((aligned(16))) unsigned short VS[2][2][64][64];

  const int tid = threadIdx.x;
  const int wid = tid >> 6;       // 0..7
  const int wq = wid & 3;         // q sub-tile
  const int kw = wid >> 2;        // key half
  const int lane = tid & 63;
  const int lr = lane & 15;
  const int lg = lane >> 4;

  // XCD-bijective swizzle: 512 blocks, 8 XCDs -> 64 contiguous per XCD
  const int bid = ((blockIdx.x & 7) << 6) + (blockIdx.x >> 3);
  const int nh = bid >> 4;
  const int q0w = ((bid & 15) << 7) + wq * 32;

  const unsigned short* gQ = Qb + ((size_t)nh * L_L + q0w) * D_H;

  // Q B-fragments (q = qb*16+lr, d = c2*32+lg*8..)
  bf16x8 bQ[2][2];
  #pragma unroll
  for (int qb = 0; qb < 2; ++qb)
    #pragma unroll
    for (int c2 = 0; c2 < 2; ++c2)
      bQ[qb][c2] = *(const bf16x8*)(gQ + (qb * 16 + lr) * D_H + c2 * 32 + lg * 8);

  const s16x8 ones16 = {0x3F80,0x3F80,0x3F80,0x3F80,0x3F80,0x3F80,0x3F80,0x3F80};
  const bf16x8 ones = *(const bf16x8*)&ones16;

  // staging: threads 0-255 stage half 0, 256-511 stage half 1
  const int sh = tid >> 8;
  const int tid8 = tid & 255;
  const int srow0 = tid8 >> 3, sch0 = tid8 & 7;
  const int srow1 = srow0 + 32;
  const int kc0 = (sch0 ^ (srow0 & 7)) * 8;  // pre-swizzled source chunk
  const int kc1 = (sch0 ^ (srow1 & 7)) * 8;
  const unsigned short* gKs = Kb + ((size_t)nh * L_L + sh * 1024) * D_H;
  const unsigned short* gVs = Vtb + (size_t)nh * D_H * L_L + sh * 1024;

  #define STAGE(buf, ktoff)                                                    \
    do {                                                                       \
      unsigned short* kd = &KS[sh][buf][0][0];                                 \
      unsigned short* vd = &VS[sh][buf][0][0];                                 \
      gload16(gKs + (size_t)((ktoff) * 64 + srow0) * D_H + kc0,                \
              kd + srow0 * 64 + sch0 * 8);                                     \
      gload16(gKs + (size_t)((ktoff) * 64 + srow1) * D_H + kc1,                \
              kd + srow1 * 64 + sch0 * 8);                                     \
      gload16(gVs + (size_t)srow0 * L_L + (ktoff) * 64 + kc0,                  \
              vd + srow0 * 64 + sch0 * 8);                                     \
      gload16(gVs + (size_t)srow1 * L_L + (ktoff) * 64 + kc1,                  \
              vd + srow1 * 64 + sch0 * 8);                                     \
    } while (0)

  STAGE(0, 0);
  __syncthreads();

  f32x4 acc0[4] = {f32x4{0,0,0,0},f32x4{0,0,0,0},f32x4{0,0,0,0},f32x4{0,0,0,0}};
  f32x4 acc1[4] = {f32x4{0,0,0,0},f32x4{0,0,0,0},f32x4{0,0,0,0},f32x4{0,0,0,0}};
  f32x4 lacc0 = {0,0,0,0}, lacc1 = {0,0,0,0};
  float m0 = -1e30f, m1 = -1e30f;
  int cur = 0;

  for (int kt = 0; kt < 16; ++kt) {
    STAGE(cur ^ 1, ((kt + 1) & 15));

    const char* Kcur = (const char*)&KS[kw][cur][0][0];
    const char* Vcur = (const char*)&VS[kw][cur][0][0];

    // QK^T swapped (A=K, B=Q): lane holds keys {16kb+4lg+r} for q = lr / 16+lr
    float sv0[16], sv1[16];
    __builtin_amdgcn_s_setprio(1);
    #pragma unroll
    for (int kb = 0; kb < 4; ++kb) {
      const int row = kb * 16 + lr;
      const bf16x8 a0 = *(const bf16x8*)(Kcur + row * 128 + ((lg ^ (row & 7)) << 4));
      const bf16x8 a1 = *(const bf16x8*)(Kcur + row * 128 + (((4 + lg) ^ (row & 7)) << 4));
      f32x4 c0 = {0,0,0,0}, c1 = {0,0,0,0};
      c0 = mfma16(a0, bQ[0][0], c0); c0 = mfma16(a1, bQ[0][1], c0);
      c1 = mfma16(a0, bQ[1][0], c1); c1 = mfma16(a1, bQ[1][1], c1);
      #pragma unroll
      for (int r = 0; r < 4; ++r) { sv0[kb*4+r] = c0[r]; sv1[kb*4+r] = c1[r]; }
    }
    __builtin_amdgcn_s_setprio(0);

    // in-lane max via v_max3 (T17)
    float mt0 = max3f(sv0[0], sv0[1], sv0[2]);
    float mt1 = max3f(sv1[0], sv1[1], sv1[2]);
    #pragma unroll
    for (int j = 3; j < 15; j += 2) {
      mt0 = max3f(mt0, sv0[j], sv0[j+1]);
      mt1 = max3f(mt1, sv1[j], sv1[j+1]);
    }
    mt0 = fmaxf(mt0, sv0[15]);
    mt1 = fmaxf(mt1, sv1[15]);

    // defer-max (T13, exp2 domain, THR=8)
    const bool defer = (mt0 - m0 <= 8.0f) && (mt1 - m1 <= 8.0f);
    if (!__all(defer)) {
      float v0 = fmaxf(mt0, __shfl_xor(mt0, 16)); v0 = fmaxf(v0, __shfl_xor(v0, 32));
      float v1 = fmaxf(mt1, __shfl_xor(mt1, 16)); v1 = fmaxf(v1, __shfl_xor(v1, 32));
      const float mn0 = fmaxf(m0, v0), mn1 = fmaxf(m1, v1);
      const float sc0f = exp2a(m0 - mn0), sc1f = exp2a(m1 - mn1);
      m0 = mn0; m1 = mn1;
      #pragma unroll
      for (int r = 0; r < 4; ++r) {
        const float sa0 = __shfl(sc0f, 4 * lg + r);
        const float sa1 = __shfl(sc1f, 4 * lg + r);
        #pragma unroll
        for (int t = 0; t < 4; ++t) { acc0[t][r] *= sa0; acc1[t][r] *= sa1; }
        lacc0[r] *= sa0; lacc1[r] *= sa1;
      }
    }

    #pragma unroll
    for (int j = 0; j < 16; ++j) {
      sv0[j] = exp2a(sv0[j] - m0);
      sv1[j] = exp2a(sv1[j] - m1);
    }

    // P -> A-fragments fully in-register (T12)
    bf16x8 aP0[2], aP1[2];
    aP0[0] = pack_frag(sv0[0], sv0[1], sv0[2], sv0[3], sv0[4], sv0[5], sv0[6], sv0[7]);
    aP0[1] = pack_frag(sv0[8], sv0[9], sv0[10], sv0[11], sv0[12], sv0[13], sv0[14], sv0[15]);
    aP1[0] = pack_frag(sv1[0], sv1[1], sv1[2], sv1[3], sv1[4], sv1[5], sv1[6], sv1[7]);
    aP1[1] = pack_frag(sv1[8], sv1[9], sv1[10], sv1[11], sv1[12], sv1[13], sv1[14], sv1[15]);

    // row-sum via ones-MFMA + PV (V B-frags from swizzled LDS)
    __builtin_amdgcn_s_setprio(1);
    lacc0 = mfma16(aP0[0], ones, lacc0); lacc0 = mfma16(aP0[1], ones, lacc0);
    lacc1 = mfma16(aP1[0], ones, lacc1); lacc1 = mfma16(aP1[1], ones, lacc1);
    #pragma unroll
    for (int t = 0; t < 4; ++t) {
      const int row = t * 16 + lr;
      const bf16x8 v0 = *(const bf16x8*)(Vcur + row * 128 + ((lg ^ (row & 7)) << 4));
      const bf16x8 v1 = *(const bf16x8*)(Vcur + row * 128 + (((4 + lg) ^ (row & 7)) << 4));
      acc0[t] = mfma16(aP0[0], v0, acc0[t]); acc0[t] = mfma16(aP0[1], v1, acc0[t]);
      acc1[t] = mfma16(aP1[0], v0, acc1[t]); acc1[t] = mfma16(aP1[1], v1, acc1[t]);
    }
    __builtin_amdgcn_s_setprio(0);

    __syncthreads();
    cur ^= 1;
  }
  #undef STAGE

  // ---- in-block split-K combine via LDS ----
  // m is per-lr; re-index to q=4lg+r to match acc/lacc layout
  float mq0[4], mq1[4];
  #pragma unroll
  for (int r = 0; r < 4; ++r) {
    mq0[r] = __shfl(m0, 4 * lg + r);
    mq1[r] = __shfl(m1, 4 * lg + r);
  }
  float* accL = (float*)&KS[0][0][0][0];  // 32 KB: exactly 4 waves x 2048 f32
  float* mlL  = (float*)&VS[0][0][0][0];  // 2 KB used
  if (kw == 1) {
    const int base = wq * 2048 + lane * 4;
    #pragma unroll
    for (int t = 0; t < 4; ++t) {
      *(f32x4*)&accL[base + t * 256] = acc0[t];
      *(f32x4*)&accL[base + 1024 + t * 256] = acc1[t];
    }
    if (lr == 0) {
      #pragma unroll
      for (int r = 0; r < 4; ++r) {
        const int q = 4 * lg + r;
        *(float2*)&mlL[wq * 128 + q * 2]      = float2{mq0[r], lacc0[r]};
        *(float2*)&mlL[wq * 128 + 64 + q * 2] = float2{mq1[r], lacc1[r]};
      }
    }
  }
  __syncthreads();
  if (kw == 0) {
    const int n = nh >> 4, h = nh & 15;
    const int base = wq * 2048 + lane * 4;
    #pragma unroll
    for (int qb = 0; qb < 2; ++qb) {
      const f32x4* accA = qb ? acc1 : acc0;
      const f32x4 lA4 = qb ? lacc1 : lacc0;
      const float* mqA = qb ? mq1 : mq0;
      #pragma unroll
      for (int r = 0; r < 4; ++r) {
        const int q = 4 * lg + r;
        const float2 mlB = *(const float2*)&mlL[wq * 128 + qb * 64 + q * 2];
        const float M = fmaxf(mqA[r], mlB.x);
        const float wA = exp2a(mqA[r] - M), wB = exp2a(mlB.x - M);
        const float invL = 1.0f / (lA4[r] * wA + mlB.y * wB);
        #pragma unroll
        for (int t = 0; t < 4; ++t) {
          const float ob = accL[base + qb * 1024 + t * 256 + r];
          const float o = (accA[t][r] * wA + ob * wB) * invL;
          Ab[((size_t)(n * L_L + q0w + qb * 16 + q)) * E_E + h * D_H + t * 16 + lr] =
              f2bf(o);
        }
      }
    }
  }
}

// K3: out = A(bf16) @ Wo^T(bf16) + bo, fp32 out. 64x64 tile, 4 waves (2x2).
__global__ __launch_bounds__(256, 4) void out_gemm_kernel(
    const unsigned short* __restrict__ Ab, const unsigned short* __restrict__ Wob,
    const float* __restrict__ bo, float* __restrict__ out) {
  __shared__ __attribute__((aligned(16))) unsigned short As[64][LDSP];
  __shared__ __attribute__((aligned(16))) unsigned short Bs[64][LDSP];
  const int tid = threadIdx.x;
  const int wid = tid >> 6;
  const int lane = tid & 63;
  const int lr = lane & 15;
  const int lg = lane >> 4;
  const int m0 = (blockIdx.x >> 4) * 64;
  const int n0 = (blockIdx.x & 15) * 64;
  const int wr = wid >> 1, wc = wid & 1;

  f32x4 acc[2][2] = {{f32x4{0,0,0,0}, f32x4{0,0,0,0}}, {f32x4{0,0,0,0}, f32x4{0,0,0,0}}};

  for (int kt = 0; kt < 16; ++kt) {
    __syncthreads();
    for (int i = tid; i < 512; i += 256) {
      const int row = i >> 3, c = i & 7;
      *(s16x8*)&As[row][c * 8] =
          *(const s16x8*)(Ab + (size_t)(m0 + row) * E_E + kt * 64 + c * 8);
      *(s16x8*)&Bs[row][c * 8] =
          *(const s16x8*)(Wob + (size_t)(n0 + row) * E_E + kt * 64 + c * 8);
    }
    __syncthreads();
    #pragma unroll
    for (int kb = 0; kb < 2; ++kb) {
      const bf16x8 a0 = *(const bf16x8*)&As[wr * 32 + lr][kb * 32 + lg * 8];
      const bf16x8 a1 = *(const bf16x8*)&As[wr * 32 + 16 + lr][kb * 32 + lg * 8];
      const bf16x8 b0 = *(const bf16x8*)&Bs[wc * 32 + lr][kb * 32 + lg * 8];
      const bf16x8 b1 = *(const bf16x8*)&Bs[wc * 32 + 16 + lr][kb * 32 + lg * 8];
      acc[0][0] = mfma16(a0, b0, acc[0][0]);
      acc[0][1] = mfma16(a0, b1, acc[0][1]);
      acc[1][0] = mfma16(a1, b0, acc[1][0]);
      acc[1][1] = mfma16(a1, b1, acc[1][1]);
    }
  }
  #pragma unroll
  for (int mi = 0; mi < 2; ++mi)
    #pragma unroll
    for (int ni = 0; ni < 2; ++ni) {
      const int nn = n0 + wc * 32 + ni * 16 + lr;
      const float bb = bo[nn];
      #pragma unroll
      for (int r = 0; r < 4; ++r) {
        const int mm = m0 + wr * 32 + mi * 16 + lg * 4 + r;
        out[(size_t)mm * E_E + nn] = acc[mi][ni][r] + bb;
      }
    }
}

extern "C" void kernel_launch(void* const* d_in, const int* in_sizes, int n_in,
                              void* d_out, int out_size, void* d_ws, size_t ws_size,
                              hipStream_t stream) {
  const float* EPq = (const float*)d_in[0];
  const float* EPk = (const float*)d_in[1];
  const float* EPv = (const float*)d_in[2];
  const float* Wq  = (const float*)d_in[3];
  const float* bq  = (const float*)d_in[4];
  const float* Wk  = (const float*)d_in[5];
  const float* bk  = (const float*)d_in[6];
  const float* Wv  = (const float*)d_in[7];
  const float* bv  = (const float*)d_in[8];
  const float* Wo  = (const float*)d_in[9];
  const float* bo  = (const float*)d_in[10];
  float* out = (float*)d_out;

  unsigned short* ws = (unsigned short*)d_ws;
  const size_t SZ = (size_t)N_B * H_H * L_L * D_H;  // 4,194,304
  unsigned short* Qb  = ws;
  unsigned short* Kb  = Qb + SZ;
  unsigned short* Vtb = Kb + SZ;
  unsigned short* Ab  = Vtb + SZ;
  unsigned short* Wob = Ab + SZ;
  unsigned short* Wqb = Wob + (size_t)E_E * E_E;
  unsigned short* Wkb = Wqb + D_H * D_H;
  unsigned short* Wvb = Wkb + D_H * D_H;

  cvt_weights_kernel<<<1027, 256, 0, stream>>>(Wo, Wq, Wk, Wv, Wob, Wqb, Wkb, Wvb);
  qkv_gemm_kernel<<<1024, 256, 0, stream>>>(
      EPq, EPk, EPv, Wqb, Wkb, Wvb, bq, bk, bv, Qb, Kb, Vtb);
  attn_mfma_kernel<<<512, 512, 0, stream>>>(Qb, Kb, Vtb, Ab);
  out_gemm_kernel<<<1024, 256, 0, stream>>>(Ab, Wob, bo, out);
}

// Round 8
// 79.690 us; speedup vs baseline: 2.0677x; 1.1458x over previous
//
#include <hip/hip_runtime.h>

#define N_B 2
#define L_L 2048
#define E_E 1024
#define H_H 16
#define D_H 64
#define LDSP 72  // padded LDS row stride (ushorts) for qkv kernel

typedef __bf16 bf16x8 __attribute__((ext_vector_type(8)));
typedef float f32x4 __attribute__((ext_vector_type(4)));
typedef short s16x8 __attribute__((ext_vector_type(8)));
typedef unsigned short u16x4 __attribute__((ext_vector_type(4)));

__device__ __forceinline__ f32x4 mfma16(bf16x8 a, bf16x8 b, f32x4 c) {
  return __builtin_amdgcn_mfma_f32_16x16x32_bf16(a, b, c, 0, 0, 0);
}

__device__ __forceinline__ unsigned short f2bf(float x) {
  unsigned int u = __float_as_uint(x);
  u = (u + 0x7fffu + ((u >> 16) & 1u)) >> 16;
  return (unsigned short)u;
}

__device__ __forceinline__ unsigned int cvtpk(float lo, float hi) {
  unsigned int r;
  asm("v_cvt_pk_bf16_f32 %0, %1, %2" : "=v"(r) : "v"(lo), "v"(hi));
  return r;
}

__device__ __forceinline__ void swap32(unsigned int& a, unsigned int& b) {
  asm("v_permlane32_swap_b32 %0, %1" : "+v"(a), "+v"(b));
}
__device__ __forceinline__ void swap16(unsigned int& a, unsigned int& b) {
  asm("v_permlane16_swap_b32 %0, %1" : "+v"(a), "+v"(b));
}

__device__ __forceinline__ float max3f(float a, float b, float c) {
  float r;
  asm("v_max3_f32 %0, %1, %2, %3" : "=v"(r) : "v"(a), "v"(b), "v"(c));
  return r;
}

__device__ __forceinline__ float exp2a(float x) {  // 2^x, single v_exp_f32
  float r;
  asm("v_exp_f32 %0, %1" : "=v"(r) : "v"(x));
  return r;
}

// async global->LDS 16B DMA (dest linear per wave)
__device__ __forceinline__ void gload16(const void* g, void* l) {
  __builtin_amdgcn_global_load_lds(
      (__attribute__((address_space(1))) void*)g,
      (__attribute__((address_space(3))) void*)l, 16, 0, 0);
}

// Build PV A-fragment from swapped-QK^T C-layout values (in-register, T12).
__device__ __forceinline__ bf16x8 pack_frag(float p0, float p1, float p2, float p3,
                                            float p4, float p5, float p6, float p7) {
  unsigned int x0 = cvtpk(p0, p1), x1 = cvtpk(p2, p3);
  unsigned int x2 = cvtpk(p4, p5), x3 = cvtpk(p6, p7);
  swap32(x0, x2); swap16(x0, x2);
  swap32(x1, x3); swap16(x1, x3);
  union { unsigned int u[4]; bf16x8 v; } f;
  f.u[0] = x0; f.u[1] = x1; f.u[2] = x2; f.u[3] = x3;
  return f.v;
}

// K1: QKV projection as MFMA GEMM. Q pre-scaled by (1/sqrt(E))*log2(e).
// Also folds: Wo fp32->bf16 conversion (4 elems/thread across the 1024-block
// grid) and in-register Wq/Wk/Wv fp32->bf16 staging (no separate cvt kernel).
__global__ __launch_bounds__(256) void qkv_gemm_kernel(
    const float* __restrict__ EPq, const float* __restrict__ EPk, const float* __restrict__ EPv,
    const float* __restrict__ Wq, const float* __restrict__ Wk, const float* __restrict__ Wv,
    const float* __restrict__ bq, const float* __restrict__ bk, const float* __restrict__ bv,
    const float* __restrict__ Wo, unsigned short* __restrict__ Wob,
    unsigned short* __restrict__ Qb, unsigned short* __restrict__ Kb,
    unsigned short* __restrict__ Vtb) {
  __shared__ __attribute__((aligned(16))) unsigned short Xs[64][LDSP];
  __shared__ __attribute__((aligned(16))) unsigned short Ws[64][LDSP];
  const int tid = threadIdx.x;
  const int wid = tid >> 6;
  const int lane = tid & 63;
  const int lr = lane & 15;
  const int lg = lane >> 4;
  const int nh = blockIdx.x >> 5;
  const int l0 = (blockIdx.x & 31) * 64;
  const int n = nh >> 4;
  const int h = nh & 15;
  const float SCQ = 0.03125f * 1.44269504089f;

  // folded Wo conversion: 1024 blocks x 256 threads x 4 elems = 1M
  {
    const int i = blockIdx.x * 256 + tid;
    const float4 f = ((const float4*)Wo)[i];
    u16x4 v = { f2bf(f.x), f2bf(f.y), f2bf(f.z), f2bf(f.w) };
    *(u16x4*)&Wob[(size_t)i * 4] = v;
  }

  #pragma unroll
  for (int mat = 0; mat < 3; ++mat) {
    const float* X = (mat == 0) ? EPq : (mat == 1) ? EPk : EPv;
    const float* W = (mat == 0) ? Wq : (mat == 1) ? Wk : Wv;
    const float* bias = (mat == 0) ? bq : (mat == 1) ? bk : bv;
    const float osc = (mat == 0) ? SCQ : 1.0f;

    const float* xb = X + ((size_t)(n * L_L + l0)) * E_E + h * D_H;
    #pragma unroll
    for (int it = 0; it < 4; ++it) {
      const int idx = it * 256 + tid;
      const int row = idx >> 4, c = idx & 15;
      const float4 f = *(const float4*)(xb + (size_t)row * E_E + c * 4);
      u16x4 v = { f2bf(f.x), f2bf(f.y), f2bf(f.z), f2bf(f.w) };
      *(u16x4*)&Xs[row][c * 4] = v;
    }
    // W staging with in-register fp32->bf16 convert
    #pragma unroll
    for (int it = 0; it < 4; ++it) {
      const int idx = it * 256 + tid;         // 1024 float4 = 4096 floats
      const int row = idx >> 4, c = idx & 15;
      const float4 f = *(const float4*)(W + idx * 4);
      u16x4 v = { f2bf(f.x), f2bf(f.y), f2bf(f.z), f2bf(f.w) };
      *(u16x4*)&Ws[row][c * 4] = v;
    }
    __syncthreads();

    const bf16x8 a0 = *(const bf16x8*)&Xs[wid * 16 + lr][lg * 8];
    const bf16x8 a1 = *(const bf16x8*)&Xs[wid * 16 + lr][32 + lg * 8];
    f32x4 acc[4];
    #pragma unroll
    for (int t = 0; t < 4; ++t) {
      const float bb = bias[t * 16 + lr];
      acc[t] = f32x4{bb, bb, bb, bb};
      const bf16x8 b0 = *(const bf16x8*)&Ws[t * 16 + lr][lg * 8];
      const bf16x8 b1 = *(const bf16x8*)&Ws[t * 16 + lr][32 + lg * 8];
      acc[t] = mfma16(a0, b0, acc[t]);
      acc[t] = mfma16(a1, b1, acc[t]);
    }
    __syncthreads();

    #pragma unroll
    for (int t = 0; t < 4; ++t)
      #pragma unroll
      for (int r = 0; r < 4; ++r)
        Xs[wid * 16 + lg * 4 + r][t * 16 + lr] = f2bf(acc[t][r] * osc);
    __syncthreads();

    if (mat < 2) {
      unsigned short* dst = ((mat == 0) ? Qb : Kb) + ((size_t)nh * L_L + l0) * D_H;
      #pragma unroll
      for (int it = 0; it < 2; ++it) {
        const int idx = it * 256 + tid;
        const int row = idx >> 3, c = idx & 7;
        *(s16x8*)(dst + (size_t)row * D_H + c * 8) = *(s16x8*)&Xs[row][c * 8];
      }
    } else {
      #pragma unroll
      for (int it = 0; it < 2; ++it) {
        const int idx = it * 256 + tid;
        const int d = idx & 63, c = idx >> 6;
        s16x8 v;
        #pragma unroll
        for (int j = 0; j < 8; ++j) v[j] = (short)Xs[c * 8 + j][d];
        *(s16x8*)(Vtb + ((size_t)nh * D_H + d) * L_L + l0 + c * 8) = v;
      }
    }
    __syncthreads();
  }
}

// K2: flash attention with in-block split-K (unchanged from round 7).
__global__ __launch_bounds__(512, 4) void attn_mfma_kernel(
    const unsigned short* __restrict__ Qb, const unsigned short* __restrict__ Kb,
    const unsigned short* __restrict__ Vtb, unsigned short* __restrict__ Ab) {
  __shared__ __attribute__((aligned(16))) unsigned short KS[2][2][64][64]; // [half][dbuf]
  __shared__ __attribute__((aligned(16))) unsigned short VS[2][2][64][64];

  const int tid = threadIdx.x;
  const int wid = tid >> 6;       // 0..7
  const int wq = wid & 3;         // q sub-tile
  const int kw = wid >> 2;        // key half
  const int lane = tid & 63;
  const int lr = lane & 15;
  const int lg = lane >> 4;

  const int bid = ((blockIdx.x & 7) << 6) + (blockIdx.x >> 3);
  const int nh = bid >> 4;
  const int q0w = ((bid & 15) << 7) + wq * 32;

  const unsigned short* gQ = Qb + ((size_t)nh * L_L + q0w) * D_H;

  bf16x8 bQ[2][2];
  #pragma unroll
  for (int qb = 0; qb < 2; ++qb)
    #pragma unroll
    for (int c2 = 0; c2 < 2; ++c2)
      bQ[qb][c2] = *(const bf16x8*)(gQ + (qb * 16 + lr) * D_H + c2 * 32 + lg * 8);

  const s16x8 ones16 = {0x3F80,0x3F80,0x3F80,0x3F80,0x3F80,0x3F80,0x3F80,0x3F80};
  const bf16x8 ones = *(const bf16x8*)&ones16;

  const int sh = tid >> 8;
  const int tid8 = tid & 255;
  const int srow0 = tid8 >> 3, sch0 = tid8 & 7;
  const int srow1 = srow0 + 32;
  const int kc0 = (sch0 ^ (srow0 & 7)) * 8;
  const int kc1 = (sch0 ^ (srow1 & 7)) * 8;
  const unsigned short* gKs = Kb + ((size_t)nh * L_L + sh * 1024) * D_H;
  const unsigned short* gVs = Vtb + (size_t)nh * D_H * L_L + sh * 1024;

  #define STAGE(buf, ktoff)                                                    \
    do {                                                                       \
      unsigned short* kd = &KS[sh][buf][0][0];                                 \
      unsigned short* vd = &VS[sh][buf][0][0];                                 \
      gload16(gKs + (size_t)((ktoff) * 64 + srow0) * D_H + kc0,                \
              kd + srow0 * 64 + sch0 * 8);                                     \
      gload16(gKs + (size_t)((ktoff) * 64 + srow1) * D_H + kc1,                \
              kd + srow1 * 64 + sch0 * 8);                                     \
      gload16(gVs + (size_t)srow0 * L_L + (ktoff) * 64 + kc0,                  \
              vd + srow0 * 64 + sch0 * 8);                                     \
      gload16(gVs + (size_t)srow1 * L_L + (ktoff) * 64 + kc1,                  \
              vd + srow1 * 64 + sch0 * 8);                                     \
    } while (0)

  STAGE(0, 0);
  __syncthreads();

  f32x4 acc0[4] = {f32x4{0,0,0,0},f32x4{0,0,0,0},f32x4{0,0,0,0},f32x4{0,0,0,0}};
  f32x4 acc1[4] = {f32x4{0,0,0,0},f32x4{0,0,0,0},f32x4{0,0,0,0},f32x4{0,0,0,0}};
  f32x4 lacc0 = {0,0,0,0}, lacc1 = {0,0,0,0};
  float m0 = -1e30f, m1 = -1e30f;
  int cur = 0;

  for (int kt = 0; kt < 16; ++kt) {
    STAGE(cur ^ 1, ((kt + 1) & 15));

    const char* Kcur = (const char*)&KS[kw][cur][0][0];
    const char* Vcur = (const char*)&VS[kw][cur][0][0];

    float sv0[16], sv1[16];
    __builtin_amdgcn_s_setprio(1);
    #pragma unroll
    for (int kb = 0; kb < 4; ++kb) {
      const int row = kb * 16 + lr;
      const bf16x8 a0 = *(const bf16x8*)(Kcur + row * 128 + ((lg ^ (row & 7)) << 4));
      const bf16x8 a1 = *(const bf16x8*)(Kcur + row * 128 + (((4 + lg) ^ (row & 7)) << 4));
      f32x4 c0 = {0,0,0,0}, c1 = {0,0,0,0};
      c0 = mfma16(a0, bQ[0][0], c0); c0 = mfma16(a1, bQ[0][1], c0);
      c1 = mfma16(a0, bQ[1][0], c1); c1 = mfma16(a1, bQ[1][1], c1);
      #pragma unroll
      for (int r = 0; r < 4; ++r) { sv0[kb*4+r] = c0[r]; sv1[kb*4+r] = c1[r]; }
    }
    __builtin_amdgcn_s_setprio(0);

    float mt0 = max3f(sv0[0], sv0[1], sv0[2]);
    float mt1 = max3f(sv1[0], sv1[1], sv1[2]);
    #pragma unroll
    for (int j = 3; j < 15; j += 2) {
      mt0 = max3f(mt0, sv0[j], sv0[j+1]);
      mt1 = max3f(mt1, sv1[j], sv1[j+1]);
    }
    mt0 = fmaxf(mt0, sv0[15]);
    mt1 = fmaxf(mt1, sv1[15]);

    const bool defer = (mt0 - m0 <= 8.0f) && (mt1 - m1 <= 8.0f);
    if (!__all(defer)) {
      float v0 = fmaxf(mt0, __shfl_xor(mt0, 16)); v0 = fmaxf(v0, __shfl_xor(v0, 32));
      float v1 = fmaxf(mt1, __shfl_xor(mt1, 16)); v1 = fmaxf(v1, __shfl_xor(v1, 32));
      const float mn0 = fmaxf(m0, v0), mn1 = fmaxf(m1, v1);
      const float sc0f = exp2a(m0 - mn0), sc1f = exp2a(m1 - mn1);
      m0 = mn0; m1 = mn1;
      #pragma unroll
      for (int r = 0; r < 4; ++r) {
        const float sa0 = __shfl(sc0f, 4 * lg + r);
        const float sa1 = __shfl(sc1f, 4 * lg + r);
        #pragma unroll
        for (int t = 0; t < 4; ++t) { acc0[t][r] *= sa0; acc1[t][r] *= sa1; }
        lacc0[r] *= sa0; lacc1[r] *= sa1;
      }
    }

    #pragma unroll
    for (int j = 0; j < 16; ++j) {
      sv0[j] = exp2a(sv0[j] - m0);
      sv1[j] = exp2a(sv1[j] - m1);
    }

    bf16x8 aP0[2], aP1[2];
    aP0[0] = pack_frag(sv0[0], sv0[1], sv0[2], sv0[3], sv0[4], sv0[5], sv0[6], sv0[7]);
    aP0[1] = pack_frag(sv0[8], sv0[9], sv0[10], sv0[11], sv0[12], sv0[13], sv0[14], sv0[15]);
    aP1[0] = pack_frag(sv1[0], sv1[1], sv1[2], sv1[3], sv1[4], sv1[5], sv1[6], sv1[7]);
    aP1[1] = pack_frag(sv1[8], sv1[9], sv1[10], sv1[11], sv1[12], sv1[13], sv1[14], sv1[15]);

    __builtin_amdgcn_s_setprio(1);
    lacc0 = mfma16(aP0[0], ones, lacc0); lacc0 = mfma16(aP0[1], ones, lacc0);
    lacc1 = mfma16(aP1[0], ones, lacc1); lacc1 = mfma16(aP1[1], ones, lacc1);
    #pragma unroll
    for (int t = 0; t < 4; ++t) {
      const int row = t * 16 + lr;
      const bf16x8 v0 = *(const bf16x8*)(Vcur + row * 128 + ((lg ^ (row & 7)) << 4));
      const bf16x8 v1 = *(const bf16x8*)(Vcur + row * 128 + (((4 + lg) ^ (row & 7)) << 4));
      acc0[t] = mfma16(aP0[0], v0, acc0[t]); acc0[t] = mfma16(aP0[1], v1, acc0[t]);
      acc1[t] = mfma16(aP1[0], v0, acc1[t]); acc1[t] = mfma16(aP1[1], v1, acc1[t]);
    }
    __builtin_amdgcn_s_setprio(0);

    __syncthreads();
    cur ^= 1;
  }
  #undef STAGE

  float mq0[4], mq1[4];
  #pragma unroll
  for (int r = 0; r < 4; ++r) {
    mq0[r] = __shfl(m0, 4 * lg + r);
    mq1[r] = __shfl(m1, 4 * lg + r);
  }
  float* accL = (float*)&KS[0][0][0][0];
  float* mlL  = (float*)&VS[0][0][0][0];
  if (kw == 1) {
    const int base = wq * 2048 + lane * 4;
    #pragma unroll
    for (int t = 0; t < 4; ++t) {
      *(f32x4*)&accL[base + t * 256] = acc0[t];
      *(f32x4*)&accL[base + 1024 + t * 256] = acc1[t];
    }
    if (lr == 0) {
      #pragma unroll
      for (int r = 0; r < 4; ++r) {
        const int q = 4 * lg + r;
        *(float2*)&mlL[wq * 128 + q * 2]      = float2{mq0[r], lacc0[r]};
        *(float2*)&mlL[wq * 128 + 64 + q * 2] = float2{mq1[r], lacc1[r]};
      }
    }
  }
  __syncthreads();
  if (kw == 0) {
    const int n = nh >> 4, h = nh & 15;
    const int base = wq * 2048 + lane * 4;
    #pragma unroll
    for (int qb = 0; qb < 2; ++qb) {
      const f32x4* accA = qb ? acc1 : acc0;
      const f32x4 lA4 = qb ? lacc1 : lacc0;
      const float* mqA = qb ? mq1 : mq0;
      #pragma unroll
      for (int r = 0; r < 4; ++r) {
        const int q = 4 * lg + r;
        const float2 mlB = *(const float2*)&mlL[wq * 128 + qb * 64 + q * 2];
        const float M = fmaxf(mqA[r], mlB.x);
        const float wA = exp2a(mqA[r] - M), wB = exp2a(mlB.x - M);
        const float invL = 1.0f / (lA4[r] * wA + mlB.y * wB);
        #pragma unroll
        for (int t = 0; t < 4; ++t) {
          const float ob = accL[base + qb * 1024 + t * 256 + r];
          const float o = (accA[t][r] * wA + ob * wB) * invL;
          Ab[((size_t)(n * L_L + q0w + qb * 16 + q)) * E_E + h * D_H + t * 16 + lr] =
              f2bf(o);
        }
      }
    }
  }
}

// K3: out = A(bf16) @ Wo^T(bf16) + bo, fp32 out.
// BM=64 x BN=128 tile, grid 512 (2 blocks/CU), global_load_lds staging with
// pre-swizzled source, double-buffered, 1 barrier/iter. 4 waves (2x2),
// each wave 32x64 output (acc[2][4]).
__global__ __launch_bounds__(256, 2) void out_gemm_kernel(
    const unsigned short* __restrict__ Ab, const unsigned short* __restrict__ Wob,
    const float* __restrict__ bo, float* __restrict__ out) {
  __shared__ __attribute__((aligned(16))) unsigned short As[2][64][64];   // 16KB
  __shared__ __attribute__((aligned(16))) unsigned short Bs[2][128][64];  // 32KB
  const int tid = threadIdx.x;
  const int wid = tid >> 6;
  const int lane = tid & 63;
  const int lr = lane & 15;
  const int lg = lane >> 4;

  // XCD swizzle: 512 blocks, 64 contiguous per XCD (8 m-tiles x all 8 n-tiles)
  const int bid = ((blockIdx.x & 7) << 6) + (blockIdx.x >> 3);
  const int m0 = (bid >> 3) * 64;
  const int n0 = (bid & 7) * 128;
  const int wr = wid >> 1, wc = wid & 1;

  // staging: A rows {r0, r0+32}, B rows {r0, +32, +64, +96}; r0 = tid>>3
  const int r0 = tid >> 3, sc = tid & 7;
  const int scol = (sc ^ (r0 & 7)) * 8;  // pre-swizzled source column (elems)

  #define OSTAGE(buf, kt)                                                      \
    do {                                                                       \
      unsigned short* ad = &As[buf][0][0];                                     \
      unsigned short* bd = &Bs[buf][0][0];                                     \
      gload16(Ab + (size_t)(m0 + r0) * E_E + (kt) * 64 + scol,                 \
              ad + r0 * 64 + sc * 8);                                          \
      gload16(Ab + (size_t)(m0 + r0 + 32) * E_E + (kt) * 64 + scol,            \
              ad + (r0 + 32) * 64 + sc * 8);                                   \
      gload16(Wob + (size_t)(n0 + r0) * E_E + (kt) * 64 + scol,                \
              bd + r0 * 64 + sc * 8);                                          \
      gload16(Wob + (size_t)(n0 + r0 + 32) * E_E + (kt) * 64 + scol,           \
              bd + (r0 + 32) * 64 + sc * 8);                                   \
      gload16(Wob + (size_t)(n0 + r0 + 64) * E_E + (kt) * 64 + scol,           \
              bd + (r0 + 64) * 64 + sc * 8);                                   \
      gload16(Wob + (size_t)(n0 + r0 + 96) * E_E + (kt) * 64 + scol,           \
              bd + (r0 + 96) * 64 + sc * 8);                                   \
    } while (0)

  f32x4 acc[2][4];
  #pragma unroll
  for (int mi = 0; mi < 2; ++mi)
    #pragma unroll
    for (int ni = 0; ni < 4; ++ni) {
      const float bb = bo[n0 + wc * 64 + ni * 16 + lr];
      acc[mi][ni] = f32x4{bb, bb, bb, bb};
    }

  OSTAGE(0, 0);
  __syncthreads();
  int cur = 0;

  for (int kt = 0; kt < 16; ++kt) {
    if (kt < 15) OSTAGE(cur ^ 1, kt + 1);

    const char* Ac = (const char*)&As[cur][0][0];
    const char* Bc = (const char*)&Bs[cur][0][0];
    bf16x8 af[2][2], bfr[4][2];
    #pragma unroll
    for (int mi = 0; mi < 2; ++mi) {
      const int row = wr * 32 + mi * 16 + lr;
      #pragma unroll
      for (int kb = 0; kb < 2; ++kb)
        af[mi][kb] = *(const bf16x8*)(Ac + row * 128 + (((kb * 4 + lg) ^ (row & 7)) << 4));
    }
    #pragma unroll
    for (int ni = 0; ni < 4; ++ni) {
      const int row = wc * 64 + ni * 16 + lr;
      #pragma unroll
      for (int kb = 0; kb < 2; ++kb)
        bfr[ni][kb] = *(const bf16x8*)(Bc + row * 128 + (((kb * 4 + lg) ^ (row & 7)) << 4));
    }
    __builtin_amdgcn_s_setprio(1);
    #pragma unroll
    for (int kb = 0; kb < 2; ++kb)
      #pragma unroll
      for (int mi = 0; mi < 2; ++mi)
        #pragma unroll
        for (int ni = 0; ni < 4; ++ni)
          acc[mi][ni] = mfma16(af[mi][kb], bfr[ni][kb], acc[mi][ni]);
    __builtin_amdgcn_s_setprio(0);

    __syncthreads();
    cur ^= 1;
  }
  #undef OSTAGE

  #pragma unroll
  for (int mi = 0; mi < 2; ++mi)
    #pragma unroll
    for (int ni = 0; ni < 4; ++ni) {
      const int nn = n0 + wc * 64 + ni * 16 + lr;
      #pragma unroll
      for (int r = 0; r < 4; ++r) {
        const int mm = m0 + wr * 32 + mi * 16 + lg * 4 + r;
        out[(size_t)mm * E_E + nn] = acc[mi][ni][r];
      }
    }
}

extern "C" void kernel_launch(void* const* d_in, const int* in_sizes, int n_in,
                              void* d_out, int out_size, void* d_ws, size_t ws_size,
                              hipStream_t stream) {
  const float* EPq = (const float*)d_in[0];
  const float* EPk = (const float*)d_in[1];
  const float* EPv = (const float*)d_in[2];
  const float* Wq  = (const float*)d_in[3];
  const float* bq  = (const float*)d_in[4];
  const float* Wk  = (const float*)d_in[5];
  const float* bk  = (const float*)d_in[6];
  const float* Wv  = (const float*)d_in[7];
  const float* bv  = (const float*)d_in[8];
  const float* Wo  = (const float*)d_in[9];
  const float* bo  = (const float*)d_in[10];
  float* out = (float*)d_out;

  unsigned short* ws = (unsigned short*)d_ws;
  const size_t SZ = (size_t)N_B * H_H * L_L * D_H;  // 4,194,304
  unsigned short* Qb  = ws;
  unsigned short* Kb  = Qb + SZ;
  unsigned short* Vtb = Kb + SZ;
  unsigned short* Ab  = Vtb + SZ;
  unsigned short* Wob = Ab + SZ;

  qkv_gemm_kernel<<<1024, 256, 0, stream>>>(
      EPq, EPk, EPv, Wq, Wk, Wv, bq, bk, bv, Wo, Wob, Qb, Kb, Vtb);
  attn_mfma_kernel<<<512, 512, 0, stream>>>(Qb, Kb, Vtb, Ab);
  out_gemm_kernel<<<512, 256, 0, stream>>>(Ab, Wob, bo, out);
}